// Round 1
// baseline (881.675 us; speedup 1.0000x reference)
//
#include <hip/hip_runtime.h>

typedef _Float16 f16;
typedef __attribute__((ext_vector_type(8))) _Float16 f16x8;
typedef __attribute__((ext_vector_type(4))) float f32x4;

#define LOG2E 1.4426950408889634f
#define MFMA16(a, b, c) __builtin_amdgcn_mfma_f32_16x16x32_f16((a), (b), (c), 0, 0, 0)

// B=2, N=2048, C=1536, H=8, D=192.  BH=16, tokens=4096.
// d_out layout: out[2,2048,1536] f32 | attn[2,8,2048,2048] f32 | M[192,192] f32

// ---------------- fp32 -> fp16 converts ----------------
__global__ void k_cvt(const float* __restrict__ src, f16* __restrict__ dst, int n4) {
    int i = blockIdx.x * blockDim.x + threadIdx.x;
    if (i >= n4) return;
    float4 v = ((const float4*)src)[i];
    union { f16 h[4]; short4 s4; } u;
    u.h[0] = (f16)v.x; u.h[1] = (f16)v.y; u.h[2] = (f16)v.z; u.h[3] = (f16)v.w;
    ((short4*)dst)[i] = u.s4;
}

// Mt[d][e] = M[e][d]  (so Mt is the B^T operand for q@M)
__global__ void k_cvtM(const float* __restrict__ M, f16* __restrict__ Mt) {
    int i = blockIdx.x * 256 + threadIdx.x;
    if (i >= 192 * 192) return;
    int d = i / 192, e = i - (i / 192) * 192;
    Mt[d * 192 + e] = (f16)M[e * 192 + d];
}

// ---------------- QKV projection GEMM ----------------
// A = x_h [4096][1536], Bw = Wqkv_h [4608][1536] (already B^T layout)
// epilogue scatters: sec0 -> Qh[bh][n][192], sec1 -> Kh[bh][n][192], sec2 -> Vt[bh][192][2048]
__global__ __launch_bounds__(256) void k_gemm_qkv(
    const f16* __restrict__ A, const f16* __restrict__ Bw,
    f16* __restrict__ Qh, f16* __restrict__ Kh, f16* __restrict__ Vt)
{
    __shared__ __align__(16) f16 As[128 * 32];
    __shared__ __align__(16) f16 Bs[128 * 32];
    const int tid = threadIdx.x;
    const int lane = tid & 63, w = tid >> 6;
    const int m0 = blockIdx.y * 128, n0 = blockIdx.x * 128;
    const int wm = (w & 1) * 64, wn = (w >> 1) * 64;
    const int L = lane & 15, g = lane >> 4;
    const char* Ab = (const char*)A;
    const char* Bb = (const char*)Bw;
    char* AsB = (char*)As; char* BsB = (char*)Bs;

    f32x4 acc[4][4] = {};
    int4 ra[2], rb[2];
    const int s0 = tid, s1 = tid + 256;
#define LD_A(kk, s) (*(const int4*)(Ab + (size_t)(m0 + ((s) >> 2)) * 3072 + (kk) * 64 + ((s) & 3) * 16))
#define LD_B(kk, s) (*(const int4*)(Bb + (size_t)(n0 + ((s) >> 2)) * 3072 + (kk) * 64 + ((s) & 3) * 16))
    ra[0] = LD_A(0, s0); ra[1] = LD_A(0, s1);
    rb[0] = LD_B(0, s0); rb[1] = LD_B(0, s1);
    for (int kk = 0; kk < 48; ++kk) {
        __syncthreads();
        *(int4*)(AsB + s0 * 16) = ra[0]; *(int4*)(AsB + s1 * 16) = ra[1];
        *(int4*)(BsB + s0 * 16) = rb[0]; *(int4*)(BsB + s1 * 16) = rb[1];
        __syncthreads();
        if (kk + 1 < 48) {
            ra[0] = LD_A(kk + 1, s0); ra[1] = LD_A(kk + 1, s1);
            rb[0] = LD_B(kk + 1, s0); rb[1] = LD_B(kk + 1, s1);
        }
        f16x8 af[4], bf[4];
#pragma unroll
        for (int i = 0; i < 4; ++i) {
            af[i] = *(const f16x8*)(AsB + (wm + i * 16 + L) * 64 + g * 16);
            bf[i] = *(const f16x8*)(BsB + (wn + i * 16 + L) * 64 + g * 16);
        }
#pragma unroll
        for (int i = 0; i < 4; ++i)
#pragma unroll
            for (int j = 0; j < 4; ++j)
                acc[i][j] = MFMA16(af[i], bf[j], acc[i][j]);
    }
#pragma unroll
    for (int i = 0; i < 4; ++i)
#pragma unroll
        for (int j = 0; j < 4; ++j) {
            int gn = n0 + wn + j * 16 + L;
            int sec = gn / 1536;
            int rem = gn - sec * 1536;
            int h = rem / 192;
            int d = rem - h * 192;
            int gm = m0 + wm + i * 16 + g * 4;
            int gb = gm >> 11, nn = gm & 2047;
            if (sec == 2) {
                union { f16 h4[4]; short4 s4; } u;
#pragma unroll
                for (int r = 0; r < 4; ++r) u.h4[r] = (f16)acc[i][j][r];
                *(short4*)(Vt + (size_t)((gb * 8 + h) * 192 + d) * 2048 + nn) = u.s4;
            } else {
                f16* dst = (sec == 0 ? Qh : Kh) + (size_t)((gb * 8 + h) * 2048 + nn) * 192 + d;
#pragma unroll
                for (int r = 0; r < 4; ++r) dst[(size_t)r * 192] = (f16)acc[i][j][r];
            }
        }
#undef LD_A
#undef LD_B
}

// ---------------- apply metric M: QM = q@M, KM = k@M ----------------
// Mt (73KB) read straight from L2; A-frags from global rows.
__global__ __launch_bounds__(256) void k_mgemm(
    const f16* __restrict__ Qh, const f16* __restrict__ Kh,
    const f16* __restrict__ Mt, f16* __restrict__ QMh, f16* __restrict__ KMh)
{
    const int tid = threadIdx.x, lane = tid & 63, w = tid >> 6;
    const int L = lane & 15, g = lane >> 4;
    const f16* src = blockIdx.y ? Kh : Qh;
    f16* dst = blockIdx.y ? KMh : QMh;
    const int row0 = blockIdx.x * 64 + w * 16;
    f16x8 af[6];
#pragma unroll
    for (int ks = 0; ks < 6; ++ks)
        af[ks] = *(const f16x8*)((const char*)src + (size_t)(row0 + L) * 384 + ks * 64 + g * 16);
    f32x4 acc[12] = {};
#pragma unroll
    for (int ct = 0; ct < 12; ++ct)
#pragma unroll
        for (int ks = 0; ks < 6; ++ks) {
            f16x8 bf = *(const f16x8*)((const char*)Mt + (ct * 16 + L) * 384 + ks * 64 + g * 16);
            acc[ct] = MFMA16(af[ks], bf, acc[ct]);
        }
#pragma unroll
    for (int ct = 0; ct < 12; ++ct)
#pragma unroll
        for (int r = 0; r < 4; ++r)
            dst[(size_t)(row0 + g * 4 + r) * 192 + ct * 16 + L] = (f16)acc[ct][r];
}

// ---------------- kMk_s[n] = (k . kM) * scale * log2e ----------------
__global__ __launch_bounds__(256) void k_kmk(
    const f16* __restrict__ Kh, const f16* __restrict__ KMh,
    const float* __restrict__ scale_p, float* __restrict__ kmk)
{
    const int tid = threadIdx.x, lane = tid & 63, w = tid >> 6;
    const int L = lane & 15;
    const int row = blockIdx.x * 16 + w * 4 + (lane >> 4);
    const char* kb = (const char*)Kh + (size_t)row * 384 + L * 24;
    const char* mb = (const char*)KMh + (size_t)row * 384 + L * 24;
    float s = 0.f;
#pragma unroll
    for (int j = 0; j < 3; ++j) {
        union { int2 i2; f16 h[4]; } a, b;
        a.i2 = *(const int2*)(kb + j * 8);
        b.i2 = *(const int2*)(mb + j * 8);
#pragma unroll
        for (int t = 0; t < 4; ++t) s += (float)a.h[t] * (float)b.h[t];
    }
    s += __shfl_xor(s, 1); s += __shfl_xor(s, 2); s += __shfl_xor(s, 4); s += __shfl_xor(s, 8);
    if (L == 0) kmk[row] = s * scale_p[0] * LOG2E;
}

// ---------------- attention phase 1: logits + online stats + unnormalized p ----------------
// grid 256: bh = bx>>4, qblock = bx&15 (128 rows). 4 waves x 32 q-rows.
// S^T tiles: mfma(A=K_chunk, B=Q_regs). lane: qrow = L (+16*qg), kcols = g*4..+3 (+16*kg)
__global__ __launch_bounds__(256) void k_attn1(
    const f16* __restrict__ QMh, const f16* __restrict__ Kh,
    const float* __restrict__ kmk, const float* __restrict__ scale_p,
    float* __restrict__ attn, float* __restrict__ mc, float* __restrict__ mlfin)
{
    __shared__ __align__(16) f16 Ks[32 * 208];   // 32 rows x 416B (padded; conflict-minimal)
    char* KsB = (char*)Ks;
    const int tid = threadIdx.x, lane = tid & 63, w = tid >> 6;
    const int bh = blockIdx.x >> 4, qb = blockIdx.x & 15;
    const int L = lane & 15, g = lane >> 4;
    const float a2 = 2.f * scale_p[0] * LOG2E;
    const int rowbase = qb * 128 + w * 32;
    const char* qbase = (const char*)QMh + (size_t)(bh * 2048 + rowbase) * 384;
    f16x8 qf[2][6];
#pragma unroll
    for (int qg = 0; qg < 2; ++qg)
#pragma unroll
        for (int ds = 0; ds < 6; ++ds)
            qf[qg][ds] = *(const f16x8*)(qbase + (qg * 16 + L) * 384 + ds * 64 + g * 16);
    const char* Kbase = (const char*)Kh + (size_t)bh * 2048 * 384;
    const float* kmkrow = kmk + bh * 2048;
    const int waveslot = blockIdx.x * 4 + w;
    float m_run[2] = {-3.0e38f, -3.0e38f};
    float l_run[2] = {0.f, 0.f};
    int4 st[3];
#pragma unroll
    for (int i = 0; i < 3; ++i) {
        int s = tid + 256 * i; int r = s / 24;
        st[i] = *(const int4*)(Kbase + (size_t)r * 384 + (s - r * 24) * 16);
    }
    for (int c = 0; c < 64; ++c) {
        __syncthreads();
#pragma unroll
        for (int i = 0; i < 3; ++i) {
            int s = tid + 256 * i; int r = s / 24;
            *(int4*)(KsB + r * 416 + (s - r * 24) * 16) = st[i];
        }
        __syncthreads();
        if (c + 1 < 64) {
#pragma unroll
            for (int i = 0; i < 3; ++i) {
                int s = tid + 256 * i; int r = s / 24;
                st[i] = *(const int4*)(Kbase + (size_t)((c + 1) * 32 + r) * 384 + (s - r * 24) * 16);
            }
        }
        f32x4 acc[2][2] = {};   // [kg][qg]
#pragma unroll
        for (int ds = 0; ds < 6; ++ds) {
            f16x8 kf0 = *(const f16x8*)(KsB + (L) * 416 + ds * 64 + g * 16);
            f16x8 kf1 = *(const f16x8*)(KsB + (16 + L) * 416 + ds * 64 + g * 16);
            acc[0][0] = MFMA16(kf0, qf[0][ds], acc[0][0]);
            acc[0][1] = MFMA16(kf0, qf[1][ds], acc[0][1]);
            acc[1][0] = MFMA16(kf1, qf[0][ds], acc[1][0]);
            acc[1][1] = MFMA16(kf1, qf[1][ds], acc[1][1]);
        }
        float4 km0 = *(const float4*)(kmkrow + c * 32 + g * 4);
        float4 km1 = *(const float4*)(kmkrow + c * 32 + 16 + g * 4);
        float kma[8] = {km0.x, km0.y, km0.z, km0.w, km1.x, km1.y, km1.z, km1.w};
        float p[2][8];
#pragma unroll
        for (int qg = 0; qg < 2; ++qg) {
#pragma unroll
            for (int r = 0; r < 4; ++r) {
                p[qg][r]     = a2 * acc[0][qg][r] - kma[r];
                p[qg][4 + r] = a2 * acc[1][qg][r] - kma[4 + r];
            }
            float mx = p[qg][0];
#pragma unroll
            for (int jj = 1; jj < 8; ++jj) mx = fmaxf(mx, p[qg][jj]);
            mx = fmaxf(mx, __shfl_xor(mx, 16));
            mx = fmaxf(mx, __shfl_xor(mx, 32));
            float mn = fmaxf(m_run[qg], mx);
            float sum = 0.f;
#pragma unroll
            for (int jj = 0; jj < 8; ++jj) {
                float e = __builtin_amdgcn_exp2f(p[qg][jj] - mn);
                p[qg][jj] = e; sum += e;
            }
            sum += __shfl_xor(sum, 16);
            sum += __shfl_xor(sum, 32);
            l_run[qg] = l_run[qg] * __builtin_amdgcn_exp2f(m_run[qg] - mn) + sum;
            m_run[qg] = mn;
            float* arow = attn + (size_t)(bh * 2048 + rowbase + qg * 16 + L) * 2048 + c * 32 + g * 4;
            *(float4*)arow = make_float4(p[qg][0], p[qg][1], p[qg][2], p[qg][3]);
            *(float4*)(arow + 16) = make_float4(p[qg][4], p[qg][5], p[qg][6], p[qg][7]);
            if (lane < 16) mc[(size_t)(waveslot * 64 + c) * 32 + qg * 16 + L] = mn;
        }
    }
    if (lane < 16) {
#pragma unroll
        for (int qg = 0; qg < 2; ++qg) {
            mlfin[(size_t)waveslot * 64 + qg * 16 + L] = m_run[qg];
            mlfin[(size_t)waveslot * 64 + 32 + qg * 16 + L] = l_run[qg];
        }
    }
}

// ---------------- attention phase 2: normalize attn in-place + PV + context ----------------
__global__ __launch_bounds__(256) void k_attn2(
    const f16* __restrict__ Vt, float* __restrict__ attn,
    const float* __restrict__ mc, const float* __restrict__ mlfin,
    f16* __restrict__ ctx)
{
    __shared__ __align__(16) f16 Vs[192 * 32];   // [192 d][32 k] rows of 64B, conflict-minimal
    char* VsB = (char*)Vs;
    const int tid = threadIdx.x, lane = tid & 63, w = tid >> 6;
    const int bh = blockIdx.x >> 4, qb = blockIdx.x & 15;
    const int L = lane & 15, g = lane >> 4;
    const int rowbase = qb * 128 + w * 32;
    const int waveslot = blockIdx.x * 4 + w;
    float mfin[2], linv[2];
#pragma unroll
    for (int qg = 0; qg < 2; ++qg) {
        mfin[qg] = mlfin[(size_t)waveslot * 64 + qg * 16 + L];
        linv[qg] = 1.f / mlfin[(size_t)waveslot * 64 + 32 + qg * 16 + L];
    }
    const char* Vbase = (const char*)Vt + (size_t)bh * 192 * 4096;
    f32x4 acc[2][12] = {};
    int4 st[3];
#pragma unroll
    for (int i = 0; i < 3; ++i) {
        int s = tid + 256 * i;
        st[i] = *(const int4*)(Vbase + (size_t)(s >> 2) * 4096 + (s & 3) * 16);
    }
    for (int c = 0; c < 64; ++c) {
        __syncthreads();
#pragma unroll
        for (int i = 0; i < 3; ++i) *(int4*)(VsB + (tid + 256 * i) * 16) = st[i];
        __syncthreads();
        if (c + 1 < 64) {
#pragma unroll
            for (int i = 0; i < 3; ++i) {
                int s = tid + 256 * i;
                st[i] = *(const int4*)(Vbase + (size_t)(s >> 2) * 4096 + (c + 1) * 64 + (s & 3) * 16);
            }
        }
        f16x8 pf[2];
#pragma unroll
        for (int qg = 0; qg < 2; ++qg) {
            float* prow = attn + (size_t)(bh * 2048 + rowbase + qg * 16 + L) * 2048 + c * 32 + g * 8;
            float4 p0 = *(const float4*)prow;
            float4 p1 = *(const float4*)(prow + 4);
            float f = __builtin_amdgcn_exp2f(mc[(size_t)(waveslot * 64 + c) * 32 + qg * 16 + L] - mfin[qg]) * linv[qg];
            p0.x *= f; p0.y *= f; p0.z *= f; p0.w *= f;
            p1.x *= f; p1.y *= f; p1.z *= f; p1.w *= f;
            *(float4*)prow = p0;
            *(float4*)(prow + 4) = p1;
            f16x8 a;
            a[0] = (f16)p0.x; a[1] = (f16)p0.y; a[2] = (f16)p0.z; a[3] = (f16)p0.w;
            a[4] = (f16)p1.x; a[5] = (f16)p1.y; a[6] = (f16)p1.z; a[7] = (f16)p1.w;
            pf[qg] = a;
        }
#pragma unroll
        for (int dt = 0; dt < 12; ++dt) {
            f16x8 bf = *(const f16x8*)(VsB + (dt * 16 + L) * 64 + g * 16);
            acc[0][dt] = MFMA16(pf[0], bf, acc[0][dt]);
            acc[1][dt] = MFMA16(pf[1], bf, acc[1][dt]);
        }
    }
    const int b = bh >> 3, h = bh & 7;
#pragma unroll
    for (int qg = 0; qg < 2; ++qg)
#pragma unroll
        for (int dt = 0; dt < 12; ++dt)
#pragma unroll
            for (int r = 0; r < 4; ++r) {
                int n = rowbase + qg * 16 + g * 4 + r;
                ctx[(size_t)(b * 2048 + n) * 1536 + h * 192 + dt * 16 + L] = (f16)acc[qg][dt][r];
            }
}

// ---------------- output projection GEMM + bias ----------------
__global__ __launch_bounds__(256) void k_proj(
    const f16* __restrict__ A, const f16* __restrict__ Bw,
    const float* __restrict__ bias, float* __restrict__ out)
{
    __shared__ __align__(16) f16 As[128 * 32];
    __shared__ __align__(16) f16 Bs[128 * 32];
    const int tid = threadIdx.x;
    const int lane = tid & 63, w = tid >> 6;
    const int m0 = blockIdx.y * 128, n0 = blockIdx.x * 128;
    const int wm = (w & 1) * 64, wn = (w >> 1) * 64;
    const int L = lane & 15, g = lane >> 4;
    const char* Ab = (const char*)A;
    const char* Bb = (const char*)Bw;
    char* AsB = (char*)As; char* BsB = (char*)Bs;

    f32x4 acc[4][4] = {};
    int4 ra[2], rb[2];
    const int s0 = tid, s1 = tid + 256;
#define LD_A(kk, s) (*(const int4*)(Ab + (size_t)(m0 + ((s) >> 2)) * 3072 + (kk) * 64 + ((s) & 3) * 16))
#define LD_B(kk, s) (*(const int4*)(Bb + (size_t)(n0 + ((s) >> 2)) * 3072 + (kk) * 64 + ((s) & 3) * 16))
    ra[0] = LD_A(0, s0); ra[1] = LD_A(0, s1);
    rb[0] = LD_B(0, s0); rb[1] = LD_B(0, s1);
    for (int kk = 0; kk < 48; ++kk) {
        __syncthreads();
        *(int4*)(AsB + s0 * 16) = ra[0]; *(int4*)(AsB + s1 * 16) = ra[1];
        *(int4*)(BsB + s0 * 16) = rb[0]; *(int4*)(BsB + s1 * 16) = rb[1];
        __syncthreads();
        if (kk + 1 < 48) {
            ra[0] = LD_A(kk + 1, s0); ra[1] = LD_A(kk + 1, s1);
            rb[0] = LD_B(kk + 1, s0); rb[1] = LD_B(kk + 1, s1);
        }
        f16x8 af[4], bf[4];
#pragma unroll
        for (int i = 0; i < 4; ++i) {
            af[i] = *(const f16x8*)(AsB + (wm + i * 16 + L) * 64 + g * 16);
            bf[i] = *(const f16x8*)(BsB + (wn + i * 16 + L) * 64 + g * 16);
        }
#pragma unroll
        for (int i = 0; i < 4; ++i)
#pragma unroll
            for (int j = 0; j < 4; ++j)
                acc[i][j] = MFMA16(af[i], bf[j], acc[i][j]);
    }
#pragma unroll
    for (int i = 0; i < 4; ++i)
#pragma unroll
        for (int j = 0; j < 4; ++j) {
            int gn = n0 + wn + j * 16 + L;
            float bv = bias[gn];
            int gm = m0 + wm + i * 16 + g * 4;
            float* dst = out + (size_t)gm * 1536 + gn;
#pragma unroll
            for (int r = 0; r < 4; ++r) dst[(size_t)r * 1536] = acc[i][j][r] + bv;
        }
#undef LD_A
#undef LD_B
}

extern "C" void kernel_launch(void* const* d_in, const int* in_sizes, int n_in,
                              void* d_out, int out_size, void* d_ws, size_t ws_size,
                              hipStream_t stream)
{
    const float* x     = (const float*)d_in[0];
    const float* Wqkv  = (const float*)d_in[1];
    const float* Wproj = (const float*)d_in[2];
    const float* bproj = (const float*)d_in[3];
    const float* scale = (const float*)d_in[4];
    const float* M     = (const float*)d_in[5];
    float* out  = (float*)d_out;
    float* attn = out + 6291456;

    char* p = (char*)d_ws;
    f16* x_h     = (f16*)p;  p += 12582912;
    f16* Wqkv_h  = (f16*)p;  p += 14155776;
    f16* Wproj_h = (f16*)p;  p += 4718592;
    f16* Mt_h    = (f16*)p;  p += 73728;
    f16* Qh      = (f16*)p;  p += 12582912;
    f16* Kh      = (f16*)p;  p += 12582912;
    f16* Vt      = (f16*)p;  p += 12582912;
    f16* QMh     = (f16*)p;  p += 12582912;
    f16* KMh     = (f16*)p;  p += 12582912;
    float* kmk   = (float*)p; p += 131072;
    float* mc    = (float*)p; p += 8388608;
    float* mlfin = (float*)p; p += 262144;
    f16* ctx     = (f16*)p;  p += 12582912;

    k_cvt<<<6144, 256, 0, stream>>>(x, x_h, 1572864);
    k_cvt<<<6912, 256, 0, stream>>>(Wqkv, Wqkv_h, 1769472);
    k_cvt<<<2304, 256, 0, stream>>>(Wproj, Wproj_h, 589824);
    k_cvtM<<<144, 256, 0, stream>>>(M, Mt_h);
    k_gemm_qkv<<<dim3(36, 32), 256, 0, stream>>>(x_h, Wqkv_h, Qh, Kh, Vt);
    k_mgemm<<<dim3(512, 2), 256, 0, stream>>>(Qh, Kh, Mt_h, QMh, KMh);
    k_kmk<<<2048, 256, 0, stream>>>(Kh, KMh, scale, kmk);
    k_attn1<<<256, 256, 0, stream>>>(QMh, Kh, kmk, scale, attn, mc, mlfin);
    k_attn2<<<256, 256, 0, stream>>>(Vt, attn, mc, mlfin, ctx);
    k_proj<<<dim3(12, 32), 256, 0, stream>>>(ctx, Wproj_h, bproj, out);
    hipMemcpyAsync(out + 73400320, M, 36864 * 4, hipMemcpyDeviceToDevice, stream);
}

// Round 2
// 822.492 us; speedup vs baseline: 1.0720x; 1.0720x over previous
//
#include <hip/hip_runtime.h>

typedef _Float16 f16;
typedef __attribute__((ext_vector_type(8))) _Float16 f16x8;
typedef __attribute__((ext_vector_type(4))) float f32x4;

#define LOG2E 1.4426950408889634f
#define MFMA16(a, b, c) __builtin_amdgcn_mfma_f32_16x16x32_f16((a), (b), (c), 0, 0, 0)

// B=2, N=2048, C=1536, H=8, D=192.  BH=16, tokens=4096.
// d_out layout: out[2,2048,1536] f32 | attn[2,8,2048,2048] f32 | M[192,192] f32

// ---------------- fp32 -> fp16 converts ----------------
__global__ void k_cvt(const float* __restrict__ src, f16* __restrict__ dst, int n4) {
    int i = blockIdx.x * blockDim.x + threadIdx.x;
    if (i >= n4) return;
    float4 v = ((const float4*)src)[i];
    union { f16 h[4]; short4 s4; } u;
    u.h[0] = (f16)v.x; u.h[1] = (f16)v.y; u.h[2] = (f16)v.z; u.h[3] = (f16)v.w;
    ((short4*)dst)[i] = u.s4;
}

// Mt[d][e] = M[e][d]  (so Mt is the B^T operand for q@M)
__global__ void k_cvtM(const float* __restrict__ M, f16* __restrict__ Mt) {
    int i = blockIdx.x * 256 + threadIdx.x;
    if (i >= 192 * 192) return;
    int d = i / 192, e = i - (i / 192) * 192;
    Mt[d * 192 + e] = (f16)M[e * 192 + d];
}

// ---------------- QKV projection GEMM ----------------
// A = x_h [4096][1536], Bw = Wqkv_h [4608][1536] (already B^T layout)
// epilogue scatters: sec0 -> Qh[bh][n][192], sec1 -> Kh[bh][n][192],
// sec2 -> Vp[bh][192][2048] with k-permuted slots within each 32-block
__global__ __launch_bounds__(256) void k_gemm_qkv(
    const f16* __restrict__ A, const f16* __restrict__ Bw,
    f16* __restrict__ Qh, f16* __restrict__ Kh, f16* __restrict__ Vp)
{
    __shared__ __align__(16) f16 As[128 * 32];
    __shared__ __align__(16) f16 Bs[128 * 32];
    const int tid = threadIdx.x;
    const int lane = tid & 63, w = tid >> 6;
    const int m0 = blockIdx.y * 128, n0 = blockIdx.x * 128;
    const int wm = (w & 1) * 64, wn = (w >> 1) * 64;
    const int L = lane & 15, g = lane >> 4;
    const char* Ab = (const char*)A;
    const char* Bb = (const char*)Bw;
    char* AsB = (char*)As; char* BsB = (char*)Bs;

    f32x4 acc[4][4] = {};
    int4 ra[2], rb[2];
    const int s0 = tid, s1 = tid + 256;
#define LD_A(kk, s) (*(const int4*)(Ab + (size_t)(m0 + ((s) >> 2)) * 3072 + (kk) * 64 + ((s) & 3) * 16))
#define LD_B(kk, s) (*(const int4*)(Bb + (size_t)(n0 + ((s) >> 2)) * 3072 + (kk) * 64 + ((s) & 3) * 16))
    ra[0] = LD_A(0, s0); ra[1] = LD_A(0, s1);
    rb[0] = LD_B(0, s0); rb[1] = LD_B(0, s1);
    for (int kk = 0; kk < 48; ++kk) {
        __syncthreads();
        *(int4*)(AsB + s0 * 16) = ra[0]; *(int4*)(AsB + s1 * 16) = ra[1];
        *(int4*)(BsB + s0 * 16) = rb[0]; *(int4*)(BsB + s1 * 16) = rb[1];
        __syncthreads();
        if (kk + 1 < 48) {
            ra[0] = LD_A(kk + 1, s0); ra[1] = LD_A(kk + 1, s1);
            rb[0] = LD_B(kk + 1, s0); rb[1] = LD_B(kk + 1, s1);
        }
        f16x8 af[4], bf[4];
#pragma unroll
        for (int i = 0; i < 4; ++i) {
            af[i] = *(const f16x8*)(AsB + (wm + i * 16 + L) * 64 + g * 16);
            bf[i] = *(const f16x8*)(BsB + (wn + i * 16 + L) * 64 + g * 16);
        }
#pragma unroll
        for (int i = 0; i < 4; ++i)
#pragma unroll
            for (int j = 0; j < 4; ++j)
                acc[i][j] = MFMA16(af[i], bf[j], acc[i][j]);
    }
#pragma unroll
    for (int i = 0; i < 4; ++i)
#pragma unroll
        for (int j = 0; j < 4; ++j) {
            int gn = n0 + wn + j * 16 + L;
            int sec = gn / 1536;
            int rem = gn - sec * 1536;
            int h = rem / 192;
            int d = rem - h * 192;
            int gm = m0 + wm + i * 16 + g * 4;
            int gb = gm >> 11, nn = gm & 2047;
            if (sec == 2) {
                union { f16 h4[4]; short4 s4; } u;
#pragma unroll
                for (int r = 0; r < 4; ++r) u.h4[r] = (f16)acc[i][j][r];
                // permuted slot: sigma^-1(nn) within each 32-token block
                int nnp = (nn & ~31) | (((nn >> 2) & 3) << 3) | (((nn >> 4) & 1) << 2);
                *(short4*)(Vp + (size_t)((gb * 8 + h) * 192 + d) * 2048 + nnp) = u.s4;
            } else {
                f16* dst = (sec == 0 ? Qh : Kh) + (size_t)((gb * 8 + h) * 2048 + nn) * 192 + d;
#pragma unroll
                for (int r = 0; r < 4; ++r) dst[(size_t)r * 192] = (f16)acc[i][j][r];
            }
        }
#undef LD_A
#undef LD_B
}

// ---------------- apply metric M: QM = q@M, KM = k@M ----------------
__global__ __launch_bounds__(256) void k_mgemm(
    const f16* __restrict__ Qh, const f16* __restrict__ Kh,
    const f16* __restrict__ Mt, f16* __restrict__ QMh, f16* __restrict__ KMh)
{
    const int tid = threadIdx.x, lane = tid & 63, w = tid >> 6;
    const int L = lane & 15, g = lane >> 4;
    const f16* src = blockIdx.y ? Kh : Qh;
    f16* dst = blockIdx.y ? KMh : QMh;
    const int row0 = blockIdx.x * 64 + w * 16;
    f16x8 af[6];
#pragma unroll
    for (int ks = 0; ks < 6; ++ks)
        af[ks] = *(const f16x8*)((const char*)src + (size_t)(row0 + L) * 384 + ks * 64 + g * 16);
    f32x4 acc[12] = {};
#pragma unroll
    for (int ct = 0; ct < 12; ++ct)
#pragma unroll
        for (int ks = 0; ks < 6; ++ks) {
            f16x8 bf = *(const f16x8*)((const char*)Mt + (ct * 16 + L) * 384 + ks * 64 + g * 16);
            acc[ct] = MFMA16(af[ks], bf, acc[ct]);
        }
#pragma unroll
    for (int ct = 0; ct < 12; ++ct)
#pragma unroll
        for (int r = 0; r < 4; ++r)
            dst[(size_t)(row0 + g * 4 + r) * 192 + ct * 16 + L] = (f16)acc[ct][r];
}

// ---------------- kMk_s[n] = (k . kM) * scale * log2e ----------------
__global__ __launch_bounds__(256) void k_kmk(
    const f16* __restrict__ Kh, const f16* __restrict__ KMh,
    const float* __restrict__ scale_p, float* __restrict__ kmk)
{
    const int tid = threadIdx.x, lane = tid & 63, w = tid >> 6;
    const int L = lane & 15;
    const int row = blockIdx.x * 16 + w * 4 + (lane >> 4);
    const char* kb = (const char*)Kh + (size_t)row * 384 + L * 24;
    const char* mb = (const char*)KMh + (size_t)row * 384 + L * 24;
    float s = 0.f;
#pragma unroll
    for (int j = 0; j < 3; ++j) {
        union { int2 i2; f16 h[4]; } a, b;
        a.i2 = *(const int2*)(kb + j * 8);
        b.i2 = *(const int2*)(mb + j * 8);
#pragma unroll
        for (int t = 0; t < 4; ++t) s += (float)a.h[t] * (float)b.h[t];
    }
    s += __shfl_xor(s, 1); s += __shfl_xor(s, 2); s += __shfl_xor(s, 4); s += __shfl_xor(s, 8);
    if (L == 0) kmk[row] = s * scale_p[0] * LOG2E;
}

// ---------------- fused two-pass flash attention ----------------
// grid 512: XCD-grouped: bh = (bx&7)*2 + (bx>>8), qb = (bx>>3)&31.
// 4 waves x 16 q-rows. Pass A: online (m,l). Pass B: recompute QK (bit-identical),
// write NORMALIZED attn + PV with k-permuted V (zero shuffles).
__global__ __launch_bounds__(256) void k_attn(
    const f16* __restrict__ QMh, const f16* __restrict__ Kh,
    const f16* __restrict__ Vp, const float* __restrict__ kmk,
    const float* __restrict__ scale_p,
    float* __restrict__ attn, f16* __restrict__ ctx)
{
    __shared__ __align__(16) char KsB[12288];    // K chunk [32][384B], XOR-swizzled
    __shared__ __align__(16) char VsB[15360];    // Vp chunk [192][64B] padded to 80B rows
    const int tid = threadIdx.x, lane = tid & 63, w = tid >> 6;
    const int L = lane & 15, g = lane >> 4;
    const int bx = blockIdx.x;
    const int bh = (bx & 7) * 2 + ((bx >> 3) >> 5);
    const int qb = (bx >> 3) & 31;
    const int row0 = qb * 64 + w * 16;
    const float a2 = 2.f * scale_p[0] * LOG2E;

    const char* qbase = (const char*)QMh + (size_t)(bh * 2048 + row0) * 384;
    f16x8 qf[6];
#pragma unroll
    for (int ks = 0; ks < 6; ++ks)
        qf[ks] = *(const f16x8*)(qbase + L * 384 + ks * 64 + g * 16);
    const char* Kbase = (const char*)Kh + (size_t)bh * 2048 * 384;
    const char* Vbase = (const char*)Vp + (size_t)bh * 192 * 4096;
    const float* kmkrow = kmk + bh * 2048;

    int ksrc[3], kdst[3], vsrc[3], vdst[3];
#pragma unroll
    for (int i = 0; i < 3; ++i) {
        int s = tid + 256 * i;
        int r = s / 24, cc = s - r * 24;
        ksrc[i] = r * 384 + cc * 16;
        kdst[i] = r * 384 + ((cc * 16) ^ ((r & 7) << 4));
        vsrc[i] = (s >> 2) * 4096 + (s & 3) * 16;
        vdst[i] = (s >> 2) * 80 + (s & 3) * 16;
    }
    const int xk = (L & 7) << 4;

    // ---------------- pass A: online max + sum ----------------
    float m_run = -3.0e38f, l_run = 0.f;
    int4 st[3];
#pragma unroll
    for (int i = 0; i < 3; ++i) st[i] = *(const int4*)(Kbase + ksrc[i]);
    for (int c = 0; c < 64; ++c) {
        __syncthreads();
#pragma unroll
        for (int i = 0; i < 3; ++i) *(int4*)(KsB + kdst[i]) = st[i];
        __syncthreads();
        if (c < 63) {
#pragma unroll
            for (int i = 0; i < 3; ++i)
                st[i] = *(const int4*)(Kbase + (size_t)(c + 1) * 12288 + ksrc[i]);
        }
        f32x4 a0 = {}, a1 = {};
#pragma unroll
        for (int ks = 0; ks < 6; ++ks) {
            f16x8 kf0 = *(const f16x8*)(KsB + L * 384 + ((ks * 64 + g * 16) ^ xk));
            f16x8 kf1 = *(const f16x8*)(KsB + (16 + L) * 384 + ((ks * 64 + g * 16) ^ xk));
            a0 = MFMA16(kf0, qf[ks], a0);
            a1 = MFMA16(kf1, qf[ks], a1);
        }
        float4 km0 = *(const float4*)(kmkrow + c * 32 + g * 4);
        float4 km1 = *(const float4*)(kmkrow + c * 32 + 16 + g * 4);
        float s8[8];
        s8[0] = a2 * a0[0] - km0.x; s8[1] = a2 * a0[1] - km0.y;
        s8[2] = a2 * a0[2] - km0.z; s8[3] = a2 * a0[3] - km0.w;
        s8[4] = a2 * a1[0] - km1.x; s8[5] = a2 * a1[1] - km1.y;
        s8[6] = a2 * a1[2] - km1.z; s8[7] = a2 * a1[3] - km1.w;
        float mx = s8[0];
#pragma unroll
        for (int j = 1; j < 8; ++j) mx = fmaxf(mx, s8[j]);
        mx = fmaxf(mx, __shfl_xor(mx, 16));
        mx = fmaxf(mx, __shfl_xor(mx, 32));
        float mn = fmaxf(m_run, mx);
        float sum = 0.f;
#pragma unroll
        for (int j = 0; j < 8; ++j) sum += __builtin_amdgcn_exp2f(s8[j] - mn);
        sum += __shfl_xor(sum, 16);
        sum += __shfl_xor(sum, 32);
        l_run = l_run * __builtin_amdgcn_exp2f(m_run - mn) + sum;
        m_run = mn;
    }
    const float moff = m_run + __log2f(l_run);   // p = exp2(s - moff) is final normalized

    // ---------------- pass B: recompute + write attn + PV ----------------
    f32x4 cacc[12] = {};
    int4 stv[3];
#pragma unroll
    for (int i = 0; i < 3; ++i) {
        st[i]  = *(const int4*)(Kbase + ksrc[i]);
        stv[i] = *(const int4*)(Vbase + vsrc[i]);
    }
    float* arow = attn + (size_t)(bh * 2048 + row0 + L) * 2048;
    for (int c = 0; c < 64; ++c) {
        __syncthreads();
#pragma unroll
        for (int i = 0; i < 3; ++i) {
            *(int4*)(KsB + kdst[i]) = st[i];
            *(int4*)(VsB + vdst[i]) = stv[i];
        }
        __syncthreads();
        if (c < 63) {
#pragma unroll
            for (int i = 0; i < 3; ++i) {
                st[i]  = *(const int4*)(Kbase + (size_t)(c + 1) * 12288 + ksrc[i]);
                stv[i] = *(const int4*)(Vbase + (size_t)(c + 1) * 64 + vsrc[i]);
            }
        }
        f32x4 a0 = {}, a1 = {};
#pragma unroll
        for (int ks = 0; ks < 6; ++ks) {
            f16x8 kf0 = *(const f16x8*)(KsB + L * 384 + ((ks * 64 + g * 16) ^ xk));
            f16x8 kf1 = *(const f16x8*)(KsB + (16 + L) * 384 + ((ks * 64 + g * 16) ^ xk));
            a0 = MFMA16(kf0, qf[ks], a0);
            a1 = MFMA16(kf1, qf[ks], a1);
        }
        float4 km0 = *(const float4*)(kmkrow + c * 32 + g * 4);
        float4 km1 = *(const float4*)(kmkrow + c * 32 + 16 + g * 4);
        float p[8];
        p[0] = __builtin_amdgcn_exp2f(a2 * a0[0] - km0.x - moff);
        p[1] = __builtin_amdgcn_exp2f(a2 * a0[1] - km0.y - moff);
        p[2] = __builtin_amdgcn_exp2f(a2 * a0[2] - km0.z - moff);
        p[3] = __builtin_amdgcn_exp2f(a2 * a0[3] - km0.w - moff);
        p[4] = __builtin_amdgcn_exp2f(a2 * a1[0] - km1.x - moff);
        p[5] = __builtin_amdgcn_exp2f(a2 * a1[1] - km1.y - moff);
        p[6] = __builtin_amdgcn_exp2f(a2 * a1[2] - km1.z - moff);
        p[7] = __builtin_amdgcn_exp2f(a2 * a1[3] - km1.w - moff);
        *(float4*)(arow + c * 32 + g * 4)      = make_float4(p[0], p[1], p[2], p[3]);
        *(float4*)(arow + c * 32 + 16 + g * 4) = make_float4(p[4], p[5], p[6], p[7]);
        f16x8 pa;
        pa[0] = (f16)p[0]; pa[1] = (f16)p[1]; pa[2] = (f16)p[2]; pa[3] = (f16)p[3];
        pa[4] = (f16)p[4]; pa[5] = (f16)p[5]; pa[6] = (f16)p[6]; pa[7] = (f16)p[7];
#pragma unroll
        for (int dt = 0; dt < 12; ++dt) {
            f16x8 vf = *(const f16x8*)(VsB + (dt * 16 + L) * 80 + g * 16);
            cacc[dt] = MFMA16(pa, vf, cacc[dt]);
        }
    }
    const int b = bh >> 3, h = bh & 7;
#pragma unroll
    for (int dt = 0; dt < 12; ++dt)
#pragma unroll
        for (int r = 0; r < 4; ++r)
            ctx[(size_t)(b * 2048 + row0 + g * 4 + r) * 1536 + h * 192 + dt * 16 + L] = (f16)cacc[dt][r];
}

// ---------------- output projection GEMM + bias ----------------
__global__ __launch_bounds__(256) void k_proj(
    const f16* __restrict__ A, const f16* __restrict__ Bw,
    const float* __restrict__ bias, float* __restrict__ out)
{
    __shared__ __align__(16) f16 As[128 * 32];
    __shared__ __align__(16) f16 Bs[128 * 32];
    const int tid = threadIdx.x;
    const int lane = tid & 63, w = tid >> 6;
    const int m0 = blockIdx.y * 128, n0 = blockIdx.x * 128;
    const int wm = (w & 1) * 64, wn = (w >> 1) * 64;
    const int L = lane & 15, g = lane >> 4;
    const char* Ab = (const char*)A;
    const char* Bb = (const char*)Bw;
    char* AsB = (char*)As; char* BsB = (char*)Bs;

    f32x4 acc[4][4] = {};
    int4 ra[2], rb[2];
    const int s0 = tid, s1 = tid + 256;
#define LD_A(kk, s) (*(const int4*)(Ab + (size_t)(m0 + ((s) >> 2)) * 3072 + (kk) * 64 + ((s) & 3) * 16))
#define LD_B(kk, s) (*(const int4*)(Bb + (size_t)(n0 + ((s) >> 2)) * 3072 + (kk) * 64 + ((s) & 3) * 16))
    ra[0] = LD_A(0, s0); ra[1] = LD_A(0, s1);
    rb[0] = LD_B(0, s0); rb[1] = LD_B(0, s1);
    for (int kk = 0; kk < 48; ++kk) {
        __syncthreads();
        *(int4*)(AsB + s0 * 16) = ra[0]; *(int4*)(AsB + s1 * 16) = ra[1];
        *(int4*)(BsB + s0 * 16) = rb[0]; *(int4*)(BsB + s1 * 16) = rb[1];
        __syncthreads();
        if (kk + 1 < 48) {
            ra[0] = LD_A(kk + 1, s0); ra[1] = LD_A(kk + 1, s1);
            rb[0] = LD_B(kk + 1, s0); rb[1] = LD_B(kk + 1, s1);
        }
        f16x8 af[4], bf[4];
#pragma unroll
        for (int i = 0; i < 4; ++i) {
            af[i] = *(const f16x8*)(AsB + (wm + i * 16 + L) * 64 + g * 16);
            bf[i] = *(const f16x8*)(BsB + (wn + i * 16 + L) * 64 + g * 16);
        }
#pragma unroll
        for (int i = 0; i < 4; ++i)
#pragma unroll
            for (int j = 0; j < 4; ++j)
                acc[i][j] = MFMA16(af[i], bf[j], acc[i][j]);
    }
#pragma unroll
    for (int i = 0; i < 4; ++i)
#pragma unroll
        for (int j = 0; j < 4; ++j) {
            int gn = n0 + wn + j * 16 + L;
            float bv = bias[gn];
            int gm = m0 + wm + i * 16 + g * 4;
            float* dst = out + (size_t)gm * 1536 + gn;
#pragma unroll
            for (int r = 0; r < 4; ++r) dst[(size_t)r * 1536] = acc[i][j][r] + bv;
        }
#undef LD_A
#undef LD_B
}

extern "C" void kernel_launch(void* const* d_in, const int* in_sizes, int n_in,
                              void* d_out, int out_size, void* d_ws, size_t ws_size,
                              hipStream_t stream)
{
    const float* x     = (const float*)d_in[0];
    const float* Wqkv  = (const float*)d_in[1];
    const float* Wproj = (const float*)d_in[2];
    const float* bproj = (const float*)d_in[3];
    const float* scale = (const float*)d_in[4];
    const float* M     = (const float*)d_in[5];
    float* out  = (float*)d_out;
    float* attn = out + 6291456;

    char* p = (char*)d_ws;
    f16* x_h     = (f16*)p;  p += 12582912;
    f16* Wqkv_h  = (f16*)p;  p += 14155776;
    f16* Wproj_h = (f16*)p;  p += 4718592;
    f16* Mt_h    = (f16*)p;  p += 73728;
    f16* Qh      = (f16*)p;  p += 12582912;
    f16* Kh      = (f16*)p;  p += 12582912;
    f16* Vp      = (f16*)p;  p += 12582912;
    f16* QMh     = (f16*)p;  p += 12582912;
    f16* KMh     = (f16*)p;  p += 12582912;
    float* kmk   = (float*)p; p += 131072;
    f16* ctx     = (f16*)p;  p += 12582912;

    k_cvt<<<6144, 256, 0, stream>>>(x, x_h, 1572864);
    k_cvt<<<6912, 256, 0, stream>>>(Wqkv, Wqkv_h, 1769472);
    k_cvt<<<2304, 256, 0, stream>>>(Wproj, Wproj_h, 589824);
    k_cvtM<<<144, 256, 0, stream>>>(M, Mt_h);
    k_gemm_qkv<<<dim3(36, 32), 256, 0, stream>>>(x_h, Wqkv_h, Qh, Kh, Vp);
    k_mgemm<<<dim3(512, 2), 256, 0, stream>>>(Qh, Kh, Mt_h, QMh, KMh);
    k_kmk<<<2048, 256, 0, stream>>>(Kh, KMh, scale, kmk);
    k_attn<<<512, 256, 0, stream>>>(QMh, Kh, Vp, kmk, scale, attn, ctx);
    k_proj<<<dim3(12, 32), 256, 0, stream>>>(ctx, Wproj_h, bproj, out);
    hipMemcpyAsync(out + 73400320, M, 36864 * 4, hipMemcpyDeviceToDevice, stream);
}